// Round 4
// baseline (181.933 us; speedup 1.0000x reference)
//
#include <hip/hip_runtime.h>
#include <hip/hip_bf16.h>

typedef _Float16 half8 __attribute__((ext_vector_type(8)));
typedef _Float16 half4v __attribute__((ext_vector_type(4)));
typedef float floatx4 __attribute__((ext_vector_type(4)));

// Problem constants: B=8, N=1024, D=512, H=8, DH=64
#define BB 8
#define NN 1024
#define DD 512
#define HH 8
#define DHH 64

// async global->LDS, 16B per lane, dest = wave-uniform base + lane*16
__device__ __forceinline__ void gload_lds16(const _Float16* g, _Float16* l) {
    __builtin_amdgcn_global_load_lds(
        (const __attribute__((address_space(1))) void*)g,
        (__attribute__((address_space(3))) void*)l, 16, 0, 0);
}

// ---------------- convert x fp32 -> fp16 (vectorized) ----------------
__global__ __launch_bounds__(256) void cvt_x_kernel(const float* __restrict__ x,
                                                    _Float16* __restrict__ xh) {
    int i = blockIdx.x * 256 + threadIdx.x;   // 4096 blocks * 256 * 4 = 4,194,304
    const float4* in = (const float4*)x;
    half4v* out = (half4v*)xh;
    float4 v = in[i];
    half4v o;
    o[0] = (_Float16)v.x; o[1] = (_Float16)v.y;
    o[2] = (_Float16)v.z; o[3] = (_Float16)v.w;
    out[i] = o;
}

// ---------------- convert + transpose W [512,512] fp32 -> Wt fp16 ----------------
__global__ __launch_bounds__(256) void cvt_w_kernel(const float* __restrict__ Wq,
                                                    const float* __restrict__ Wk,
                                                    const float* __restrict__ Wv,
                                                    _Float16* __restrict__ Wt) {
    __shared__ __align__(16) _Float16 tb[64][72];
    int which = blockIdx.z;
    const float* W = (which == 0) ? Wq : (which == 1) ? Wk : Wv;
    _Float16* Wto = Wt + (size_t)which * DD * DD;
    int kt = blockIdx.y * 64, nt = blockIdx.x * 64;
    int tid = threadIdx.x;
    for (int i = 0; i < 16; i++) {
        int idx = tid + i * 256;
        int r = idx >> 6, c = idx & 63;
        tb[c][r] = (_Float16)W[(size_t)(kt + r) * DD + nt + c];
    }
    __syncthreads();
    for (int i = 0; i < 16; i++) {
        int idx = tid + i * 256;
        int r = idx >> 6, c = idx & 63;
        Wto[(size_t)(nt + r) * DD + kt + c] = tb[r][c];
    }
}

// ---------------- QKV projection, 128x128 tile, global_load_lds ----------------
__global__ __launch_bounds__(256) void qkv_gemm_kernel(const _Float16* __restrict__ xh,
                                                       const _Float16* __restrict__ Wt,
                                                       const float* __restrict__ bq,
                                                       const float* __restrict__ bk,
                                                       const float* __restrict__ bv,
                                                       _Float16* __restrict__ QKV) {
    __shared__ __align__(16) _Float16 As[128 * 32];
    __shared__ __align__(16) _Float16 Bs[128 * 32];

    int which = blockIdx.z;
    const _Float16* Wtw = Wt + (size_t)which * DD * DD;
    const float* bias = (which == 0) ? bq : (which == 1) ? bk : bv;

    int tid = threadIdx.x;
    int wave = tid >> 6, lane = tid & 63;
    int quad = lane >> 4, l16 = lane & 15;
    int wm = wave >> 1, wn = wave & 1;
    int mBase = blockIdx.y * 128, nBase = blockIdx.x * 128;

    int srow = wave * 32 + (lane >> 2);
    int scol = (lane & 3) * 8;
    const _Float16* ag = xh  + (size_t)(mBase + srow) * DD + scol;
    const _Float16* bg = Wtw + (size_t)(nBase + srow) * DD + scol;
    _Float16* al = As + (wave * 32) * 32;
    _Float16* bl = Bs + (wave * 32) * 32;

    floatx4 acc[4][4];
    for (int mt = 0; mt < 4; mt++)
        for (int nt = 0; nt < 4; nt++) acc[mt][nt] = (floatx4){0.f, 0.f, 0.f, 0.f};

    for (int kk = 0; kk < DD; kk += 32) {
        __syncthreads();
        gload_lds16(ag + kk,            al);
        gload_lds16(ag + 16 * DD + kk,  al + 16 * 32);
        gload_lds16(bg + kk,            bl);
        gload_lds16(bg + 16 * DD + kk,  bl + 16 * 32);
        __syncthreads();

        half8 af[4], bf[4];
        for (int mt = 0; mt < 4; mt++)
            af[mt] = *(const half8*)&As[(wm * 64 + mt * 16 + l16) * 32 + quad * 8];
        for (int nt = 0; nt < 4; nt++)
            bf[nt] = *(const half8*)&Bs[(wn * 64 + nt * 16 + l16) * 32 + quad * 8];
        for (int mt = 0; mt < 4; mt++)
            for (int nt = 0; nt < 4; nt++)
                acc[mt][nt] = __builtin_amdgcn_mfma_f32_16x16x32_f16(af[mt], bf[nt], acc[mt][nt], 0, 0, 0);
    }

    if (which < 2) {
        _Float16* out = QKV + (size_t)which * (BB * NN) * DD;
        for (int nt = 0; nt < 4; nt++) {
            int col = nBase + wn * 64 + nt * 16 + l16;
            float bval = bias[col];
            for (int mt = 0; mt < 4; mt++) {
                int row0 = mBase + wm * 64 + mt * 16 + quad * 4;
                for (int reg = 0; reg < 4; reg++)
                    out[(size_t)(row0 + reg) * DD + col] = (_Float16)(acc[mt][nt][reg] + bval);
            }
        }
    } else {
        // V transposed: VT[(b*512 + col)*1024 + n]
        _Float16* VT = QKV + (size_t)2 * (BB * NN) * DD;
        for (int nt = 0; nt < 4; nt++) {
            int col = nBase + wn * 64 + nt * 16 + l16;
            float bval = bias[col];
            for (int mt = 0; mt < 4; mt++) {
                int row0 = mBase + wm * 64 + mt * 16 + quad * 4;
                int b = row0 >> 10;
                int n = row0 & 1023;
                half4v pack;
                for (int reg = 0; reg < 4; reg++) pack[reg] = (_Float16)(acc[mt][nt][reg] + bval);
                *(half4v*)&VT[((size_t)b * 512 + col) * 1024 + n] = pack;
            }
        }
    }
}

// ---------------- flash attention, S^T formulation, O^T PV ----------------
// grid (16 qtiles, 8 heads, 8 batch), block 256 (4 waves). Br=64 (16 q-rows/wave), Bc=128.
// S^T = K*Q^T (C-layout: col=l16=q, row=quad*4+reg=key) -> per-lane stats for q=l16.
// P routed through per-wave LDS strip PT[q][key] (b64 packed writes, b128 frag reads).
// PV computed as O^T = V^T * P^T (A=V-frag, B=P-frag): C-layout col=l16=q, so
// alpha/l_i apply per-lane with no broadcasts; epilogue stores float4.
__global__ __launch_bounds__(256) void attn_kernel(const _Float16* __restrict__ QKV,
                                                   float* __restrict__ out) {
    const _Float16* Q  = QKV;
    const _Float16* K  = QKV + (size_t)(BB * NN) * DD;
    const _Float16* VT = QKV + (size_t)2 * (BB * NN) * DD;

    __shared__ __align__(16) _Float16 Kt[128 * 64];    // [key][d]
    __shared__ __align__(16) _Float16 Vt[64 * 128];    // [d][key]
    __shared__ __align__(16) _Float16 PT[4][16][136];  // per-wave [q][key], stride 136

    int tid = threadIdx.x;
    int wave = tid >> 6, lane = tid & 63;
    int quad = lane >> 4, l16 = lane & 15;
    int qt = blockIdx.x, h = blockIdx.y, b = blockIdx.z;

    const _Float16* Qb  = Q + ((size_t)b * NN) * DD + h * DHH;
    const _Float16* Kb  = K + ((size_t)b * NN) * DD + h * DHH;
    const _Float16* VTb = VT + ((size_t)b * 512 + h * 64) * 1024;

    // Q fragment (B-operand for S^T: B[k=d][n=q], lane n=l16 holds Q[qrow(l16)][d])
    int qrow = qt * 64 + wave * 16 + l16;
    half8 qf0 = *(const half8*)(Qb + (size_t)qrow * DD + 0 * 32 + quad * 8);
    half8 qf1 = *(const half8*)(Qb + (size_t)qrow * DD + 1 * 32 + quad * 8);

    floatx4 o[4];
    for (int nt = 0; nt < 4; nt++) o[nt] = (floatx4){0.f, 0.f, 0.f, 0.f};
    float m_i = -1e30f, l_i = 0.f;

    const _Float16* kg = Kb + (size_t)(wave * 32 + (lane >> 3)) * DD + (lane & 7) * 8;
    _Float16* kl = Kt + (wave * 32) * 64;
    const _Float16* vg = VTb + (size_t)(wave * 16 + (lane >> 4)) * 1024 + (lane & 15) * 8;
    _Float16* vl = Vt + (wave * 16) * 128;

    for (int kt = 0; kt < 8; kt++) {
        __syncthreads();
        for (int i = 0; i < 4; i++)
            gload_lds16(kg + (size_t)(kt * 128 + i * 8) * DD, kl + (i * 8) * 64);
        for (int i = 0; i < 4; i++)
            gload_lds16(vg + (size_t)(i * 4) * 1024 + kt * 128, vl + (i * 4) * 128);
        __syncthreads();

        // S^T: A = K-frag (m=key), B = Q-frag (n=q). s[nt][reg]: q=l16, key=nt*16+quad*4+reg
        floatx4 s[8];
        for (int nt = 0; nt < 8; nt++) s[nt] = (floatx4){0.f, 0.f, 0.f, 0.f};
        for (int ks = 0; ks < 2; ks++) {
            half8 qf = ks ? qf1 : qf0;
            for (int nt = 0; nt < 8; nt++) {
                half8 kf = *(const half8*)&Kt[(nt * 16 + l16) * 64 + ks * 32 + quad * 8];
                s[nt] = __builtin_amdgcn_mfma_f32_16x16x32_f16(kf, qf, s[nt], 0, 0, 0);
            }
        }

        // per-lane row stats for q-row l16 (combine 4 quads via 2 shuffles)
        float mx = -1e30f;
        for (int nt = 0; nt < 8; nt++)
            for (int r = 0; r < 4; r++) mx = fmaxf(mx, s[nt][r]);
        mx = fmaxf(mx, __shfl_xor(mx, 16, 64));
        mx = fmaxf(mx, __shfl_xor(mx, 32, 64));
        float mnew = fmaxf(m_i, mx);
        float alpha = __expf(m_i - mnew);
        m_i = mnew;
        float rs = 0.f;
        for (int nt = 0; nt < 8; nt++)
            for (int r = 0; r < 4; r++) {
                float p = __expf(s[nt][r] - mnew);
                s[nt][r] = p;
                rs += p;
            }
        rs += __shfl_xor(rs, 16, 64);
        rs += __shfl_xor(rs, 32, 64);
        l_i = l_i * alpha + rs;

        // P^T -> LDS: lane holds 4 consecutive keys (nt*16+quad*4+r) of row l16.
        // 8x ds_write_b64; wave-internal RAW (no barrier; per-wave strip).
        for (int nt = 0; nt < 8; nt++) {
            half4v p4;
            for (int r = 0; r < 4; r++) p4[r] = (_Float16)s[nt][r];
            *(half4v*)&PT[wave][l16][nt * 16 + quad * 4] = p4;
        }

        // rescale O (col=l16=q for all regs): own-lane alpha
        for (int nt = 0; nt < 4; nt++)
            for (int r = 0; r < 4; r++) o[nt][r] *= alpha;

        // O^T += V^T P^T: A = V-frag (m=dh), B = P-frag (n=q=l16, k=key)
        for (int ks2 = 0; ks2 < 4; ks2++) {
            half8 pf = *(const half8*)&PT[wave][l16][ks2 * 32 + quad * 8];
            for (int nt = 0; nt < 4; nt++) {
                half8 vf = *(const half8*)&Vt[(nt * 16 + l16) * 128 + ks2 * 32 + quad * 8];
                o[nt] = __builtin_amdgcn_mfma_f32_16x16x32_f16(vf, pf, o[nt], 0, 0, 0);
            }
        }
    }

    // epilogue: o[nt][reg] = O[q=l16][dh=nt*16+quad*4+reg]; own-lane l_i; float4 stores
    float inv = 1.0f / l_i;
    float* outb = out + ((size_t)b * NN) * DD + h * DHH;
    int row = qt * 64 + wave * 16 + l16;
    for (int nt = 0; nt < 4; nt++) {
        float4 st;
        st.x = o[nt][0] * inv; st.y = o[nt][1] * inv;
        st.z = o[nt][2] * inv; st.w = o[nt][3] * inv;
        *(float4*)&outb[(size_t)row * DD + nt * 16 + quad * 4] = st;
    }
}

extern "C" void kernel_launch(void* const* d_in, const int* in_sizes, int n_in,
                              void* d_out, int out_size, void* d_ws, size_t ws_size,
                              hipStream_t stream) {
    const float* x  = (const float*)d_in[0];
    const float* Wq = (const float*)d_in[1];
    const float* bq = (const float*)d_in[2];
    const float* Wk = (const float*)d_in[3];
    const float* bk = (const float*)d_in[4];
    const float* Wv = (const float*)d_in[5];
    const float* bv = (const float*)d_in[6];
    float* out = (float*)d_out;

    _Float16* xh  = (_Float16*)d_ws;
    _Float16* Wt  = xh + (size_t)(BB * NN) * DD;
    _Float16* QKV = Wt + (size_t)3 * DD * DD;

    hipLaunchKernelGGL(cvt_x_kernel, dim3(4096), dim3(256), 0, stream, x, xh);
    hipLaunchKernelGGL(cvt_w_kernel, dim3(8, 8, 3), dim3(256), 0, stream, Wq, Wk, Wv, Wt);
    hipLaunchKernelGGL(qkv_gemm_kernel, dim3(4, 64, 3), dim3(256), 0, stream,
                       xh, Wt, bq, bk, bv, QKV);
    hipLaunchKernelGGL(attn_kernel, dim3(16, 8, 8), dim3(256), 0, stream, QKV, out);
}

// Round 5
// 148.832 us; speedup vs baseline: 1.2224x; 1.2224x over previous
//
#include <hip/hip_runtime.h>
#include <hip/hip_bf16.h>

typedef _Float16 half8 __attribute__((ext_vector_type(8)));
typedef _Float16 half4v __attribute__((ext_vector_type(4)));
typedef float floatx4 __attribute__((ext_vector_type(4)));

// Problem constants: B=8, N=1024, D=512, H=8, DH=64
#define BB 8
#define NN 1024
#define DD 512
#define HH 8
#define DHH 64

// async global->LDS, 16B per lane, dest = wave-uniform base + lane*16
__device__ __forceinline__ void gload_lds16(const _Float16* g, _Float16* l) {
    __builtin_amdgcn_global_load_lds(
        (const __attribute__((address_space(1))) void*)g,
        (__attribute__((address_space(3))) void*)l, 16, 0, 0);
}

// ---------------- convert x fp32 -> fp16 (vectorized) ----------------
__global__ __launch_bounds__(256) void cvt_x_kernel(const float* __restrict__ x,
                                                    _Float16* __restrict__ xh) {
    int i = blockIdx.x * 256 + threadIdx.x;   // 4096 blocks * 256 * 4 = 4,194,304
    const float4* in = (const float4*)x;
    half4v* out = (half4v*)xh;
    float4 v = in[i];
    half4v o;
    o[0] = (_Float16)v.x; o[1] = (_Float16)v.y;
    o[2] = (_Float16)v.z; o[3] = (_Float16)v.w;
    out[i] = o;
}

// ---------------- convert + transpose W [512,512] fp32 -> Wt fp16 ----------------
__global__ __launch_bounds__(256) void cvt_w_kernel(const float* __restrict__ Wq,
                                                    const float* __restrict__ Wk,
                                                    const float* __restrict__ Wv,
                                                    _Float16* __restrict__ Wt) {
    __shared__ __align__(16) _Float16 tb[64][72];
    int which = blockIdx.z;
    const float* W = (which == 0) ? Wq : (which == 1) ? Wk : Wv;
    _Float16* Wto = Wt + (size_t)which * DD * DD;
    int kt = blockIdx.y * 64, nt = blockIdx.x * 64;
    int tid = threadIdx.x;
    for (int i = 0; i < 16; i++) {
        int idx = tid + i * 256;
        int r = idx >> 6, c = idx & 63;
        tb[c][r] = (_Float16)W[(size_t)(kt + r) * DD + nt + c];
    }
    __syncthreads();
    for (int i = 0; i < 16; i++) {
        int idx = tid + i * 256;
        int r = idx >> 6, c = idx & 63;
        Wto[(size_t)(nt + r) * DD + kt + c] = tb[r][c];
    }
}

// ---------------- QKV projection, 128x128 tile, global_load_lds ----------------
__global__ __launch_bounds__(256) void qkv_gemm_kernel(const _Float16* __restrict__ xh,
                                                       const _Float16* __restrict__ Wt,
                                                       const float* __restrict__ bq,
                                                       const float* __restrict__ bk,
                                                       const float* __restrict__ bv,
                                                       _Float16* __restrict__ QKV) {
    __shared__ __align__(16) _Float16 As[128 * 32];
    __shared__ __align__(16) _Float16 Bs[128 * 32];

    int which = blockIdx.z;
    const _Float16* Wtw = Wt + (size_t)which * DD * DD;
    const float* bias = (which == 0) ? bq : (which == 1) ? bk : bv;

    int tid = threadIdx.x;
    int wave = tid >> 6, lane = tid & 63;
    int quad = lane >> 4, l16 = lane & 15;
    int wm = wave >> 1, wn = wave & 1;
    int mBase = blockIdx.y * 128, nBase = blockIdx.x * 128;

    int srow = wave * 32 + (lane >> 2);
    int scol = (lane & 3) * 8;
    const _Float16* ag = xh  + (size_t)(mBase + srow) * DD + scol;
    const _Float16* bg = Wtw + (size_t)(nBase + srow) * DD + scol;
    _Float16* al = As + (wave * 32) * 32;
    _Float16* bl = Bs + (wave * 32) * 32;

    floatx4 acc[4][4];
    for (int mt = 0; mt < 4; mt++)
        for (int nt = 0; nt < 4; nt++) acc[mt][nt] = (floatx4){0.f, 0.f, 0.f, 0.f};

    for (int kk = 0; kk < DD; kk += 32) {
        __syncthreads();
        gload_lds16(ag + kk,            al);
        gload_lds16(ag + 16 * DD + kk,  al + 16 * 32);
        gload_lds16(bg + kk,            bl);
        gload_lds16(bg + 16 * DD + kk,  bl + 16 * 32);
        __syncthreads();

        half8 af[4], bf[4];
        for (int mt = 0; mt < 4; mt++)
            af[mt] = *(const half8*)&As[(wm * 64 + mt * 16 + l16) * 32 + quad * 8];
        for (int nt = 0; nt < 4; nt++)
            bf[nt] = *(const half8*)&Bs[(wn * 64 + nt * 16 + l16) * 32 + quad * 8];
        for (int mt = 0; mt < 4; mt++)
            for (int nt = 0; nt < 4; nt++)
                acc[mt][nt] = __builtin_amdgcn_mfma_f32_16x16x32_f16(af[mt], bf[nt], acc[mt][nt], 0, 0, 0);
    }

    if (which < 2) {
        _Float16* out = QKV + (size_t)which * (BB * NN) * DD;
        for (int nt = 0; nt < 4; nt++) {
            int col = nBase + wn * 64 + nt * 16 + l16;
            float bval = bias[col];
            for (int mt = 0; mt < 4; mt++) {
                int row0 = mBase + wm * 64 + mt * 16 + quad * 4;
                for (int reg = 0; reg < 4; reg++)
                    out[(size_t)(row0 + reg) * DD + col] = (_Float16)(acc[mt][nt][reg] + bval);
            }
        }
    } else {
        // V transposed: VT[(b*512 + col)*1024 + n]
        _Float16* VT = QKV + (size_t)2 * (BB * NN) * DD;
        for (int nt = 0; nt < 4; nt++) {
            int col = nBase + wn * 64 + nt * 16 + l16;
            float bval = bias[col];
            for (int mt = 0; mt < 4; mt++) {
                int row0 = mBase + wm * 64 + mt * 16 + quad * 4;
                int b = row0 >> 10;
                int n = row0 & 1023;
                half4v pack;
                for (int reg = 0; reg < 4; reg++) pack[reg] = (_Float16)(acc[mt][nt][reg] + bval);
                *(half4v*)&VT[((size_t)b * 512 + col) * 1024 + n] = pack;
            }
        }
    }
}

// ---------------- flash attention, S^T formulation, XOR-swizzled LDS ----------------
// grid (16,8,8), block 256 (4 waves). Br=64 (16 q/wave), Bc=128.
// All LDS tiles store 16B chunk c of row r at physical chunk c ^ (r mod nchunks):
// fragment-read bank = 4*(c^l16)+w -> 2 lanes/bank (free, m136); staging picks the
// matching global chunk per lane so global_load_lds stays legal (dest contiguous).
// LDS = 16K(Kt) + 16K(Vt) + 8K(PT) = 40960 B -> exactly 4 blocks/CU, grid 1024 = 256*4.
__global__ __launch_bounds__(256) void attn_kernel(const _Float16* __restrict__ QKV,
                                                   float* __restrict__ out) {
    const _Float16* Q  = QKV;
    const _Float16* K  = QKV + (size_t)(BB * NN) * DD;
    const _Float16* VT = QKV + (size_t)2 * (BB * NN) * DD;

    __shared__ __align__(16) _Float16 Kt[128 * 64];   // [key][d], 8 chunks/row, swizzled
    __shared__ __align__(16) _Float16 Vt[64 * 128];   // [d][key], 16 chunks/row, swizzled
    __shared__ __align__(16) _Float16 PT[4][16 * 64]; // per-wave [q][64 keys], 8 chunks/row

    int tid = threadIdx.x;
    int wave = tid >> 6, lane = tid & 63;
    int quad = lane >> 4, l16 = lane & 15;
    int qt = blockIdx.x, h = blockIdx.y, b = blockIdx.z;

    const _Float16* Qb  = Q + ((size_t)b * NN) * DD + h * DHH;
    const _Float16* Kb  = K + ((size_t)b * NN) * DD + h * DHH;
    const _Float16* VTb = VT + ((size_t)b * 512 + h * 64) * 1024;

    // Q fragment (B-operand for S^T)
    int qrow = qt * 64 + wave * 16 + l16;
    half8 qf0 = *(const half8*)(Qb + (size_t)qrow * DD + 0 * 32 + quad * 8);
    half8 qf1 = *(const half8*)(Qb + (size_t)qrow * DD + 1 * 32 + quad * 8);

    floatx4 o[4];
    for (int nt = 0; nt < 4; nt++) o[nt] = (floatx4){0.f, 0.f, 0.f, 0.f};
    float m_i = -1e30f, l_i = 0.f;

    // Kt staging: instr covers 8 rows x 128B; lane: row_local=lane>>3, phys chunk=lane&7,
    // row&7 == row_local for all 4 issues -> logical chunk = (lane&7)^(lane>>3), fixed.
    const _Float16* kg = Kb + (size_t)(wave * 32 + (lane >> 3)) * DD
                            + ((lane & 7) ^ (lane >> 3)) * 8;
    _Float16* kl = Kt + (wave * 32) * 64;
    _Float16* vl = Vt + (wave * 16) * 128;
    int l16sw = l16 & 7;

    for (int kt = 0; kt < 8; kt++) {
        __syncthreads();
        for (int i = 0; i < 4; i++)
            gload_lds16(kg + (size_t)(kt * 128 + i * 8) * DD, kl + (i * 8) * 64);
        // Vt staging: instr covers 4 rows x 256B; row&15 = i*4 + (lane>>4) varies per i.
        for (int i = 0; i < 4; i++) {
            int vrow = wave * 16 + i * 4 + (lane >> 4);
            int vc = (lane & 15) ^ (i * 4 + (lane >> 4));
            gload_lds16(VTb + (size_t)vrow * 1024 + kt * 128 + vc * 8, vl + (i * 4) * 128);
        }
        __syncthreads();

        // S^T: A = K-frag (m=key), B = Q-frag (n=q). s[nt][r]: q=l16, key=nt*16+quad*4+r
        floatx4 s[8];
        for (int nt = 0; nt < 8; nt++) s[nt] = (floatx4){0.f, 0.f, 0.f, 0.f};
        for (int ks = 0; ks < 2; ks++) {
            half8 qf = ks ? qf1 : qf0;
            for (int nt = 0; nt < 8; nt++) {
                half8 kf = *(const half8*)&Kt[(nt * 16 + l16) * 64
                                              + (((ks * 4 + quad) ^ l16sw) * 8)];
                s[nt] = __builtin_amdgcn_mfma_f32_16x16x32_f16(kf, qf, s[nt], 0, 0, 0);
            }
        }

        // per-lane row stats for q-row l16 (combine 4 quads via 2 shuffles)
        float mx = -1e30f;
        for (int nt = 0; nt < 8; nt++)
            for (int r = 0; r < 4; r++) mx = fmaxf(mx, s[nt][r]);
        mx = fmaxf(mx, __shfl_xor(mx, 16, 64));
        mx = fmaxf(mx, __shfl_xor(mx, 32, 64));
        float mnew = fmaxf(m_i, mx);
        float alpha = __expf(m_i - mnew);
        m_i = mnew;
        float rs = 0.f;
        for (int nt = 0; nt < 8; nt++)
            for (int r = 0; r < 4; r++) {
                float p = __expf(s[nt][r] - mnew);
                s[nt][r] = p;
                rs += p;
            }
        rs += __shfl_xor(rs, 16, 64);
        rs += __shfl_xor(rs, 32, 64);
        l_i = l_i * alpha + rs;

        // rescale O (col=l16=q for all regs): own-lane alpha
        for (int nt = 0; nt < 4; nt++)
            for (int r = 0; r < 4; r++) o[nt][r] *= alpha;

        // PV in two 64-key halves through the per-wave swizzled PT strip.
        // Writes: lane holds keys ntl*16+quad*4..+3 of row l16 -> chunk 2*ntl+(quad>>1),
        // 8B half (quad&1). Reads: B-frag chunk ks2h*4+quad. DS ops are wave-internal
        // and in-order (lgkm DS FIFO), so the half1-write / half0-read WAR is safe.
        for (int hh = 0; hh < 2; hh++) {
            for (int ntl = 0; ntl < 4; ntl++) {
                floatx4 sv = s[hh * 4 + ntl];
                half4v p4;
                for (int r = 0; r < 4; r++) p4[r] = (_Float16)sv[r];
                *(half4v*)&PT[wave][l16 * 64 + (((2 * ntl + (quad >> 1)) ^ l16sw) * 8)
                               + (quad & 1) * 4] = p4;
            }
            for (int ks2h = 0; ks2h < 2; ks2h++) {
                half8 pf = *(const half8*)&PT[wave][l16 * 64
                                                   + (((ks2h * 4 + quad) ^ l16sw) * 8)];
                int ks2 = hh * 2 + ks2h;
                for (int nt = 0; nt < 4; nt++) {
                    half8 vf = *(const half8*)&Vt[(nt * 16 + l16) * 128
                                                  + (((ks2 * 4 + quad) ^ l16) * 8)];
                    o[nt] = __builtin_amdgcn_mfma_f32_16x16x32_f16(vf, pf, o[nt], 0, 0, 0);
                }
            }
        }
    }

    // epilogue: o[nt][r] = O[q=l16][dh=nt*16+quad*4+r]; own-lane l_i; float4 stores
    float inv = 1.0f / l_i;
    float* outb = out + ((size_t)b * NN) * DD + h * DHH;
    int row = qt * 64 + wave * 16 + l16;
    for (int nt = 0; nt < 4; nt++) {
        float4 st;
        st.x = o[nt][0] * inv; st.y = o[nt][1] * inv;
        st.z = o[nt][2] * inv; st.w = o[nt][3] * inv;
        *(float4*)&outb[(size_t)row * DD + nt * 16 + quad * 4] = st;
    }
}

extern "C" void kernel_launch(void* const* d_in, const int* in_sizes, int n_in,
                              void* d_out, int out_size, void* d_ws, size_t ws_size,
                              hipStream_t stream) {
    const float* x  = (const float*)d_in[0];
    const float* Wq = (const float*)d_in[1];
    const float* bq = (const float*)d_in[2];
    const float* Wk = (const float*)d_in[3];
    const float* bk = (const float*)d_in[4];
    const float* Wv = (const float*)d_in[5];
    const float* bv = (const float*)d_in[6];
    float* out = (float*)d_out;

    _Float16* xh  = (_Float16*)d_ws;
    _Float16* Wt  = xh + (size_t)(BB * NN) * DD;
    _Float16* QKV = Wt + (size_t)3 * DD * DD;

    hipLaunchKernelGGL(cvt_x_kernel, dim3(4096), dim3(256), 0, stream, x, xh);
    hipLaunchKernelGGL(cvt_w_kernel, dim3(8, 8, 3), dim3(256), 0, stream, Wq, Wk, Wv, Wt);
    hipLaunchKernelGGL(qkv_gemm_kernel, dim3(4, 64, 3), dim3(256), 0, stream,
                       xh, Wt, bq, bk, bv, QKV);
    hipLaunchKernelGGL(attn_kernel, dim3(16, 8, 8), dim3(256), 0, stream, QKV, out);
}

// Round 6
// 142.039 us; speedup vs baseline: 1.2809x; 1.0478x over previous
//
#include <hip/hip_runtime.h>
#include <hip/hip_bf16.h>

typedef _Float16 half8 __attribute__((ext_vector_type(8)));
typedef _Float16 half4v __attribute__((ext_vector_type(4)));
typedef float floatx4 __attribute__((ext_vector_type(4)));

// Problem constants: B=8, N=1024, D=512, H=8, DH=64
#define BB 8
#define NN 1024
#define DD 512
#define HH 8
#define DHH 64

// async global->LDS, 16B per lane, dest = wave-uniform base + lane*16
__device__ __forceinline__ void gload_lds16(const _Float16* g, _Float16* l) {
    __builtin_amdgcn_global_load_lds(
        (const __attribute__((address_space(1))) void*)g,
        (__attribute__((address_space(3))) void*)l, 16, 0, 0);
}

// ---------------- fused conversion: x fp32->fp16, W fp32->fp16 transposed ----------------
// blocks [0,4096): x convert (float4 -> half4). blocks [4096,4288): W transpose tiles.
__global__ __launch_bounds__(256) void cvt_kernel(const float* __restrict__ x,
                                                  const float* __restrict__ Wq,
                                                  const float* __restrict__ Wk,
                                                  const float* __restrict__ Wv,
                                                  _Float16* __restrict__ xh,
                                                  _Float16* __restrict__ Wt) {
    __shared__ __align__(16) _Float16 tb[64][72];
    int bx = blockIdx.x;
    int tid = threadIdx.x;
    if (bx < 4096) {
        int i = bx * 256 + tid;
        float4 v = ((const float4*)x)[i];
        half4v o;
        o[0] = (_Float16)v.x; o[1] = (_Float16)v.y;
        o[2] = (_Float16)v.z; o[3] = (_Float16)v.w;
        ((half4v*)xh)[i] = o;
        return;
    }
    int t = bx - 4096;                 // 0..191
    int which = t >> 6;                // /64
    int rem = t & 63;
    int kt = (rem >> 3) * 64, nt = (rem & 7) * 64;
    const float* W = (which == 0) ? Wq : (which == 1) ? Wk : Wv;
    _Float16* Wto = Wt + (size_t)which * DD * DD;
    for (int i = 0; i < 16; i++) {
        int idx = tid + i * 256;
        int r = idx >> 6, c = idx & 63;
        tb[c][r] = (_Float16)W[(size_t)(kt + r) * DD + nt + c];   // coalesced read
    }
    __syncthreads();
    for (int i = 0; i < 16; i++) {
        int idx = tid + i * 256;
        int r = idx >> 6, c = idx & 63;
        Wto[(size_t)(nt + r) * DD + kt + c] = tb[r][c];           // coalesced write
    }
}

// ---------------- QKV projection, 128x128 tile, global_load_lds ----------------
// For which<2 (Q,K): A-operand = W rows (features), B = x rows (tokens) -> C rows are
// FEATURES, cols are tokens: lane holds 4 consecutive features of one token -> half4v
// row-major stores (kills the 64x scalar-2B store pattern). For which==2 (V): A = x,
// B = W (C rows = tokens) -> VT[feature][token] half4v stores as before.
__global__ __launch_bounds__(256) void qkv_gemm_kernel(const _Float16* __restrict__ xh,
                                                       const _Float16* __restrict__ Wt,
                                                       const float* __restrict__ bq,
                                                       const float* __restrict__ bk,
                                                       const float* __restrict__ bv,
                                                       _Float16* __restrict__ QKV) {
    __shared__ __align__(16) _Float16 As[128 * 32];
    __shared__ __align__(16) _Float16 Bs[128 * 32];

    int which = blockIdx.z;
    const _Float16* Wtw = Wt + (size_t)which * DD * DD;
    const float* bias = (which == 0) ? bq : (which == 1) ? bk : bv;

    int tid = threadIdx.x;
    int wave = tid >> 6, lane = tid & 63;
    int quad = lane >> 4, l16 = lane & 15;
    int wm = wave >> 1, wn = wave & 1;
    int mBase = blockIdx.y * 128;   // tokens
    int nBase = blockIdx.x * 128;   // features

    int srow = wave * 32 + (lane >> 2);
    int scol = (lane & 3) * 8;
    // A-rows / B-rows chosen per which (K-loop itself is identical)
    const _Float16* ag = (which < 2)
        ? Wtw + (size_t)(nBase + srow) * DD + scol
        : xh  + (size_t)(mBase + srow) * DD + scol;
    const _Float16* bg = (which < 2)
        ? xh  + (size_t)(mBase + srow) * DD + scol
        : Wtw + (size_t)(nBase + srow) * DD + scol;
    _Float16* al = As + (wave * 32) * 32;
    _Float16* bl = Bs + (wave * 32) * 32;

    floatx4 acc[4][4];
    for (int i = 0; i < 4; i++)
        for (int j = 0; j < 4; j++) acc[i][j] = (floatx4){0.f, 0.f, 0.f, 0.f};

    for (int kk = 0; kk < DD; kk += 32) {
        __syncthreads();
        gload_lds16(ag + kk,            al);
        gload_lds16(ag + 16 * DD + kk,  al + 16 * 32);
        gload_lds16(bg + kk,            bl);
        gload_lds16(bg + 16 * DD + kk,  bl + 16 * 32);
        __syncthreads();

        half8 af[4], bf[4];
        for (int i = 0; i < 4; i++)
            af[i] = *(const half8*)&As[(wm * 64 + i * 16 + l16) * 32 + quad * 8];
        for (int j = 0; j < 4; j++)
            bf[j] = *(const half8*)&Bs[(wn * 64 + j * 16 + l16) * 32 + quad * 8];
        for (int i = 0; i < 4; i++)
            for (int j = 0; j < 4; j++)
                acc[i][j] = __builtin_amdgcn_mfma_f32_16x16x32_f16(af[i], bf[j], acc[i][j], 0, 0, 0);
    }

    if (which < 2) {
        // C rows = features (A=W), cols = tokens (B=x).
        // acc[i][j]: feature = nBase + wm*64 + i*16 + quad*4 + reg, token = mBase + wn*64 + j*16 + l16
        _Float16* out = QKV + (size_t)which * (BB * NN) * DD;
        for (int i = 0; i < 4; i++) {
            int feat0 = nBase + wm * 64 + i * 16 + quad * 4;
            float4 b4 = *(const float4*)&bias[feat0];
            for (int j = 0; j < 4; j++) {
                int token = mBase + wn * 64 + j * 16 + l16;
                half4v pack;
                pack[0] = (_Float16)(acc[i][j][0] + b4.x);
                pack[1] = (_Float16)(acc[i][j][1] + b4.y);
                pack[2] = (_Float16)(acc[i][j][2] + b4.z);
                pack[3] = (_Float16)(acc[i][j][3] + b4.w);
                *(half4v*)&out[(size_t)token * DD + feat0] = pack;
            }
        }
    } else {
        // C rows = tokens, cols = features. VT[(b*512 + feat)*1024 + n], 4 regs = consecutive n.
        _Float16* VT = QKV + (size_t)2 * (BB * NN) * DD;
        for (int j = 0; j < 4; j++) {
            int col = nBase + wn * 64 + j * 16 + l16;
            float bval = bias[col];
            for (int i = 0; i < 4; i++) {
                int row0 = mBase + wm * 64 + i * 16 + quad * 4;
                int b = row0 >> 10;
                int n = row0 & 1023;
                half4v pack;
                for (int reg = 0; reg < 4; reg++) pack[reg] = (_Float16)(acc[i][j][reg] + bval);
                *(half4v*)&VT[((size_t)b * 512 + col) * 1024 + n] = pack;
            }
        }
    }
}

// ---------------- flash attention, S^T formulation, XOR-swizzled LDS ----------------
// grid (16,8,8), block 256 (4 waves). Br=64 (16 q/wave), Bc=128.
// (unchanged from round 5 — 78.9 -> ~45 us with swizzle)
__global__ __launch_bounds__(256) void attn_kernel(const _Float16* __restrict__ QKV,
                                                   float* __restrict__ out) {
    const _Float16* Q  = QKV;
    const _Float16* K  = QKV + (size_t)(BB * NN) * DD;
    const _Float16* VT = QKV + (size_t)2 * (BB * NN) * DD;

    __shared__ __align__(16) _Float16 Kt[128 * 64];   // [key][d], 8 chunks/row, swizzled
    __shared__ __align__(16) _Float16 Vt[64 * 128];   // [d][key], 16 chunks/row, swizzled
    __shared__ __align__(16) _Float16 PT[4][16 * 64]; // per-wave [q][64 keys]

    int tid = threadIdx.x;
    int wave = tid >> 6, lane = tid & 63;
    int quad = lane >> 4, l16 = lane & 15;
    int qt = blockIdx.x, h = blockIdx.y, b = blockIdx.z;

    const _Float16* Qb  = Q + ((size_t)b * NN) * DD + h * DHH;
    const _Float16* Kb  = K + ((size_t)b * NN) * DD + h * DHH;
    const _Float16* VTb = VT + ((size_t)b * 512 + h * 64) * 1024;

    int qrow = qt * 64 + wave * 16 + l16;
    half8 qf0 = *(const half8*)(Qb + (size_t)qrow * DD + 0 * 32 + quad * 8);
    half8 qf1 = *(const half8*)(Qb + (size_t)qrow * DD + 1 * 32 + quad * 8);

    floatx4 o[4];
    for (int nt = 0; nt < 4; nt++) o[nt] = (floatx4){0.f, 0.f, 0.f, 0.f};
    float m_i = -1e30f, l_i = 0.f;

    const _Float16* kg = Kb + (size_t)(wave * 32 + (lane >> 3)) * DD
                            + ((lane & 7) ^ (lane >> 3)) * 8;
    _Float16* kl = Kt + (wave * 32) * 64;
    _Float16* vl = Vt + (wave * 16) * 128;
    int l16sw = l16 & 7;

    for (int kt = 0; kt < 8; kt++) {
        __syncthreads();
        for (int i = 0; i < 4; i++)
            gload_lds16(kg + (size_t)(kt * 128 + i * 8) * DD, kl + (i * 8) * 64);
        for (int i = 0; i < 4; i++) {
            int vrow = wave * 16 + i * 4 + (lane >> 4);
            int vc = (lane & 15) ^ (i * 4 + (lane >> 4));
            gload_lds16(VTb + (size_t)vrow * 1024 + kt * 128 + vc * 8, vl + (i * 4) * 128);
        }
        __syncthreads();

        floatx4 s[8];
        for (int nt = 0; nt < 8; nt++) s[nt] = (floatx4){0.f, 0.f, 0.f, 0.f};
        for (int ks = 0; ks < 2; ks++) {
            half8 qf = ks ? qf1 : qf0;
            for (int nt = 0; nt < 8; nt++) {
                half8 kf = *(const half8*)&Kt[(nt * 16 + l16) * 64
                                              + (((ks * 4 + quad) ^ l16sw) * 8)];
                s[nt] = __builtin_amdgcn_mfma_f32_16x16x32_f16(kf, qf, s[nt], 0, 0, 0);
            }
        }

        float mx = -1e30f;
        for (int nt = 0; nt < 8; nt++)
            for (int r = 0; r < 4; r++) mx = fmaxf(mx, s[nt][r]);
        mx = fmaxf(mx, __shfl_xor(mx, 16, 64));
        mx = fmaxf(mx, __shfl_xor(mx, 32, 64));
        float mnew = fmaxf(m_i, mx);
        float alpha = __expf(m_i - mnew);
        m_i = mnew;
        float rs = 0.f;
        for (int nt = 0; nt < 8; nt++)
            for (int r = 0; r < 4; r++) {
                float p = __expf(s[nt][r] - mnew);
                s[nt][r] = p;
                rs += p;
            }
        rs += __shfl_xor(rs, 16, 64);
        rs += __shfl_xor(rs, 32, 64);
        l_i = l_i * alpha + rs;

        for (int nt = 0; nt < 4; nt++)
            for (int r = 0; r < 4; r++) o[nt][r] *= alpha;

        for (int hh = 0; hh < 2; hh++) {
            for (int ntl = 0; ntl < 4; ntl++) {
                floatx4 sv = s[hh * 4 + ntl];
                half4v p4;
                for (int r = 0; r < 4; r++) p4[r] = (_Float16)sv[r];
                *(half4v*)&PT[wave][l16 * 64 + (((2 * ntl + (quad >> 1)) ^ l16sw) * 8)
                               + (quad & 1) * 4] = p4;
            }
            for (int ks2h = 0; ks2h < 2; ks2h++) {
                half8 pf = *(const half8*)&PT[wave][l16 * 64
                                                   + (((ks2h * 4 + quad) ^ l16sw) * 8)];
                int ks2 = hh * 2 + ks2h;
                for (int nt = 0; nt < 4; nt++) {
                    half8 vf = *(const half8*)&Vt[(nt * 16 + l16) * 128
                                                  + (((ks2 * 4 + quad) ^ l16) * 8)];
                    o[nt] = __builtin_amdgcn_mfma_f32_16x16x32_f16(vf, pf, o[nt], 0, 0, 0);
                }
            }
        }
    }

    float inv = 1.0f / l_i;
    float* outb = out + ((size_t)b * NN) * DD + h * DHH;
    int row = qt * 64 + wave * 16 + l16;
    for (int nt = 0; nt < 4; nt++) {
        float4 st;
        st.x = o[nt][0] * inv; st.y = o[nt][1] * inv;
        st.z = o[nt][2] * inv; st.w = o[nt][3] * inv;
        *(float4*)&outb[(size_t)row * DD + nt * 16 + quad * 4] = st;
    }
}

extern "C" void kernel_launch(void* const* d_in, const int* in_sizes, int n_in,
                              void* d_out, int out_size, void* d_ws, size_t ws_size,
                              hipStream_t stream) {
    const float* x  = (const float*)d_in[0];
    const float* Wq = (const float*)d_in[1];
    const float* bq = (const float*)d_in[2];
    const float* Wk = (const float*)d_in[3];
    const float* bk = (const float*)d_in[4];
    const float* Wv = (const float*)d_in[5];
    const float* bv = (const float*)d_in[6];
    float* out = (float*)d_out;

    _Float16* xh  = (_Float16*)d_ws;
    _Float16* Wt  = xh + (size_t)(BB * NN) * DD;
    _Float16* QKV = Wt + (size_t)3 * DD * DD;

    hipLaunchKernelGGL(cvt_kernel, dim3(4096 + 192), dim3(256), 0, stream,
                       x, Wq, Wk, Wv, xh, Wt);
    hipLaunchKernelGGL(qkv_gemm_kernel, dim3(4, 64, 3), dim3(256), 0, stream,
                       xh, Wt, bq, bk, bv, QKV);
    hipLaunchKernelGGL(attn_kernel, dim3(16, 8, 8), dim3(256), 0, stream, QKV, out);
}